// Round 8
// baseline (102.149 us; speedup 1.0000x reference)
//
#include <hip/hip_runtime.h>
#include <hip/hip_bf16.h>
#include <math.h>

#define N_NODES 50000
#define N_EDGES 800000
#define IN_F 256
#define OUT_F 64

#define HIST_CHUNK 12500   // nodes per LDS histogram chunk (4 chunks)
#define HIST_SLICES 16     // edge slices per (array, chunk)

#define BKT 256            // nodes per dst-bucket
#define NB 196             // ceil(50000/256)
#define PARTA_BLOCKS 200   // edge slices in pass A (800000/200 = 4000/block)

typedef __attribute__((ext_vector_type(8))) short bf16x8;
typedef __attribute__((ext_vector_type(4))) float f32x4;

__device__ __forceinline__ ushort f2bf(float x) {
    __hip_bfloat16 b = __float2bfloat16(x);   // RNE
    return *reinterpret_cast<ushort*>(&b);
}
__device__ __forceinline__ float bf_lo(uint v) { return __uint_as_float(v << 16); }
__device__ __forceinline__ float bf_hi(uint v) { return __uint_as_float(v & 0xffff0000u); }

// ---------------------------------------------------------------------------
// 0) Zero the degree arrays + counter ourselves. The HIP runtime's
//    fillBufferAligned runs at ~10 GB/s on this 400 KB odd-size fill
//    (41 us = 40% of total!). 25001 int4 coalesced stores = ~2-3 us.
// ---------------------------------------------------------------------------
__global__ __launch_bounds__(256) void zero_kernel(int4* __restrict__ p, int n4) {
    const int i = blockIdx.x * blockDim.x + threadIdx.x;
    if (i < n4) p[i] = (int4){0, 0, 0, 0};
}

// ---------------------------------------------------------------------------
// 1) Degree counting via LDS-privatized histograms.
// ---------------------------------------------------------------------------
__global__ __launch_bounds__(256) void hist_kernel(const int* __restrict__ src,
                                                   const int* __restrict__ dst,
                                                   int* __restrict__ outdeg,
                                                   int* __restrict__ indeg) {
    __shared__ int cnt[HIST_CHUNK];   // 50 KB
    const int bi = blockIdx.x;
    const int arr = bi >> 6;
    const int chunk = (bi >> 4) & 3;
    const int slice = bi & 15;
    const int* __restrict__ data = arr ? dst : src;
    int* __restrict__ glob = arr ? indeg : outdeg;
    const int base = chunk * HIST_CHUNK;

    for (int i = threadIdx.x; i < HIST_CHUNK; i += 256) cnt[i] = 0;
    __syncthreads();

    const int4* d4 = (const int4*)(data + (size_t)slice * (N_EDGES / HIST_SLICES));
    for (int i = threadIdx.x; i < (N_EDGES / HIST_SLICES) / 4; i += 256) {
        const int4 v = d4[i];
        int r;
        r = v.x - base; if ((unsigned)r < (unsigned)HIST_CHUNK) atomicAdd(&cnt[r], 1);
        r = v.y - base; if ((unsigned)r < (unsigned)HIST_CHUNK) atomicAdd(&cnt[r], 1);
        r = v.z - base; if ((unsigned)r < (unsigned)HIST_CHUNK) atomicAdd(&cnt[r], 1);
        r = v.w - base; if ((unsigned)r < (unsigned)HIST_CHUNK) atomicAdd(&cnt[r], 1);
    }
    __syncthreads();

    for (int i = threadIdx.x; i < HIST_CHUNK; i += 256) {
        const int c = cnt[i];
        if (c) atomicAdd(&glob[base + i], c);
    }
}

// ---------------------------------------------------------------------------
// 2) Bucket-ordered allocation: one block per 256-node bucket. Intra-block
//    exclusive scan of indeg; ONE global atomicAdd per bucket.
// ---------------------------------------------------------------------------
__global__ __launch_bounds__(256) void alloc_kernel(const int* __restrict__ indeg,
                                                    int* __restrict__ ptr,
                                                    int* __restrict__ bucketBase,
                                                    int* __restrict__ gcursor,
                                                    int* __restrict__ counter) {
    __shared__ int wtot[4];
    __shared__ int sbase;
    const int b = blockIdx.x;
    const int tid = threadIdx.x;
    const int lane = tid & 63;
    const int wave = tid >> 6;
    const int node = b * BKT + tid;
    const int v = (node < N_NODES) ? indeg[node] : 0;
    int incl = v;
    #pragma unroll
    for (int d = 1; d < 64; d <<= 1) {
        int u = __shfl_up(incl, d, 64);
        if (lane >= d) incl += u;
    }
    if (lane == 63) wtot[wave] = incl;
    __syncthreads();
    int woff = 0, total = 0;
    #pragma unroll
    for (int w = 0; w < 4; ++w) {
        const int t = wtot[w];
        if (w < wave) woff += t;
        total += t;
    }
    if (tid == 0) sbase = atomicAdd(counter, total);
    __syncthreads();
    const int base = sbase;
    if (node < N_NODES) ptr[node] = base + woff + incl - v;
    if (tid == 0) { bucketBase[b] = base; gcursor[b] = base; }
}

// ---------------------------------------------------------------------------
// 3a) Pass A: partition edges into 196 dst-buckets, packed as
//     (dst&255)<<16 | src.
// ---------------------------------------------------------------------------
__global__ __launch_bounds__(256) void partA_kernel(const int* __restrict__ src,
                                                    const int* __restrict__ dst,
                                                    int* __restrict__ gcursor,
                                                    uint* __restrict__ pairs) {
    __shared__ int lcnt[NB];
    __shared__ int lbase[NB];
    const int tid = threadIdx.x;
    const int EPB = N_EDGES / PARTA_BLOCKS;   // 4000
    const int n4 = EPB / 4;                   // 1000

    for (int i = tid; i < NB; i += 256) lcnt[i] = 0;
    __syncthreads();

    const int4* t4 = (const int4*)(dst + (size_t)blockIdx.x * EPB);
    const int4* s4 = (const int4*)(src + (size_t)blockIdx.x * EPB);

    for (int i = tid; i < n4; i += 256) {
        const int4 d = t4[i];
        atomicAdd(&lcnt[d.x >> 8], 1);
        atomicAdd(&lcnt[d.y >> 8], 1);
        atomicAdd(&lcnt[d.z >> 8], 1);
        atomicAdd(&lcnt[d.w >> 8], 1);
    }
    __syncthreads();

    for (int i = tid; i < NB; i += 256) {
        const int c = lcnt[i];
        lbase[i] = c ? atomicAdd(&gcursor[i], c) : 0;
        lcnt[i] = 0;
    }
    __syncthreads();

    for (int i = tid; i < n4; i += 256) {
        const int4 d = t4[i];
        const int4 s = s4[i];
        int bx, off;
        bx = d.x >> 8; off = atomicAdd(&lcnt[bx], 1);
        pairs[lbase[bx] + off] = ((uint)(d.x & 255) << 16) | (uint)s.x;
        bx = d.y >> 8; off = atomicAdd(&lcnt[bx], 1);
        pairs[lbase[bx] + off] = ((uint)(d.y & 255) << 16) | (uint)s.y;
        bx = d.z >> 8; off = atomicAdd(&lcnt[bx], 1);
        pairs[lbase[bx] + off] = ((uint)(d.z & 255) << 16) | (uint)s.z;
        bx = d.w >> 8; off = atomicAdd(&lcnt[bx], 1);
        pairs[lbase[bx] + off] = ((uint)(d.w & 255) << 16) | (uint)s.w;
    }
}

// ---------------------------------------------------------------------------
// 3b) Pass B: within one bucket, place each src at ptr[dst]+pos via LDS
//     cursors.
// ---------------------------------------------------------------------------
__global__ __launch_bounds__(256) void partB_kernel(const uint* __restrict__ pairs,
                                                    const int* __restrict__ ptr,
                                                    const int* __restrict__ bucketBase,
                                                    const int* __restrict__ gcursor,
                                                    int* __restrict__ sorted_src) {
    __shared__ int lptr[BKT];
    __shared__ int lcur[BKT];
    const int b = blockIdx.x;
    const int tid = threadIdx.x;
    const int node = b * BKT + tid;
    lptr[tid] = (node < N_NODES) ? ptr[node] : 0;
    lcur[tid] = 0;
    __syncthreads();
    const int base = bucketBase[b];
    const int cnt = gcursor[b] - base;
    for (int i = tid; i < cnt; i += 256) {
        const uint p = pairs[base + i];
        const int local = (int)(p >> 16);
        const int pos = atomicAdd(&lcur[local], 1);
        sorted_src[lptr[local] + pos] = (int)(p & 0xFFFFu);
    }
}

// ---------------------------------------------------------------------------
// 4) h = bf16( norm_src * (feat @ W) ) via MFMA 16x16x32 bf16.
// ---------------------------------------------------------------------------
__global__ __launch_bounds__(256) void gemm_kernel(const float* __restrict__ feat,
                                                   const float* __restrict__ W,
                                                   const int* __restrict__ outdeg,
                                                   ushort* __restrict__ h) {
    const int lane = threadIdx.x & 63;
    const int wave = threadIdx.x >> 6;
    const int m = lane & 15;
    const int g = lane >> 4;
    const int rowBase = blockIdx.x * 256 + wave * 64;

    f32x4 acc[4][4];
    #pragma unroll
    for (int rt = 0; rt < 4; ++rt)
        #pragma unroll
        for (int ct = 0; ct < 4; ++ct)
            acc[rt][ct] = (f32x4){0.f, 0.f, 0.f, 0.f};

    #pragma unroll 2
    for (int step = 0; step < 8; ++step) {
        const int k0 = step * 32 + g * 8;

        bf16x8 bfr[4];
        #pragma unroll
        for (int ct = 0; ct < 4; ++ct) {
            const float* wp = W + (size_t)k0 * OUT_F + ct * 16 + m;
            bf16x8 bb;
            #pragma unroll
            for (int j = 0; j < 8; ++j) bb[j] = (short)f2bf(wp[(size_t)j * OUT_F]);
            bfr[ct] = bb;
        }

        #pragma unroll
        for (int rt = 0; rt < 4; ++rt) {
            int row = rowBase + rt * 16 + m;
            if (row >= N_NODES) row = 0;
            const float* ap = feat + (size_t)row * IN_F + k0;
            const float4 a0 = *(const float4*)ap;
            const float4 a1 = *(const float4*)(ap + 4);
            bf16x8 aa;
            aa[0] = (short)f2bf(a0.x); aa[1] = (short)f2bf(a0.y);
            aa[2] = (short)f2bf(a0.z); aa[3] = (short)f2bf(a0.w);
            aa[4] = (short)f2bf(a1.x); aa[5] = (short)f2bf(a1.y);
            aa[6] = (short)f2bf(a1.z); aa[7] = (short)f2bf(a1.w);
            #pragma unroll
            for (int ct = 0; ct < 4; ++ct)
                acc[rt][ct] = __builtin_amdgcn_mfma_f32_16x16x32_bf16(
                    aa, bfr[ct], acc[rt][ct], 0, 0, 0);
        }
    }

    #pragma unroll
    for (int rt = 0; rt < 4; ++rt) {
        #pragma unroll
        for (int j = 0; j < 4; ++j) {
            const int row = rowBase + rt * 16 + g * 4 + j;
            if (row < N_NODES) {
                const float norm = rsqrtf(fmaxf((float)outdeg[row], 1.0f));
                #pragma unroll
                for (int ct = 0; ct < 4; ++ct)
                    h[(size_t)row * OUT_F + ct * 16 + m] = f2bf(acc[rt][ct][j] * norm);
            }
        }
    }
}

// ---------------------------------------------------------------------------
// 5) Gather + epilogue: one wave per dst node, 2 edges per iteration.
// ---------------------------------------------------------------------------
__global__ __launch_bounds__(256) void gather_kernel(const int* __restrict__ ptr,
                                                     const int* __restrict__ indeg,
                                                     const int* __restrict__ sorted_src,
                                                     const ushort* __restrict__ h,
                                                     const float* __restrict__ b,
                                                     float* __restrict__ out) {
    const int lane = threadIdx.x & 63;
    const int half = lane >> 5;
    const int cl = lane & 31;
    int nid = (int)((blockIdx.x * (size_t)blockDim.x + threadIdx.x) >> 6);
    if (nid >= N_NODES) return;
    nid = __builtin_amdgcn_readfirstlane(nid);

    const int beg = ptr[nid];
    const int deg = indeg[nid];

    float ax = 0.f, ay = 0.f;
    const int nfull = deg >> 1;
    int e = beg + half;
    #pragma unroll 4
    for (int i = 0; i < nfull; ++i) {
        const int s = sorted_src[e];
        e += 2;
        const uint v = *(const uint*)(h + (size_t)s * OUT_F + cl * 2);
        ax += bf_lo(v);
        ay += bf_hi(v);
    }
    if ((deg & 1) && half == 0) {
        const int s = sorted_src[beg + deg - 1];
        const uint v = *(const uint*)(h + (size_t)s * OUT_F + cl * 2);
        ax += bf_lo(v);
        ay += bf_hi(v);
    }
    ax += __shfl_xor(ax, 32, 64);
    ay += __shfl_xor(ay, 32, 64);

    if (half == 0) {
        const float norm = rsqrtf(fmaxf((float)deg, 1.0f));
        const float x0 = ax * norm + b[cl * 2 + 0];
        const float x1 = ay * norm + b[cl * 2 + 1];
        float2 o;
        o.x = 1.0f / (1.0f + expf(-x0));
        o.y = 1.0f / (1.0f + expf(-x1));
        *(float2*)(out + (size_t)nid * OUT_F + cl * 2) = o;
    }
}

// ---------------------------------------------------------------------------
extern "C" void kernel_launch(void* const* d_in, const int* in_sizes, int n_in,
                              void* d_out, int out_size, void* d_ws, size_t ws_size,
                              hipStream_t stream) {
    const float* feat = (const float*)d_in[0];
    const int* src    = (const int*)d_in[1];
    const int* dst    = (const int*)d_in[2];
    const float* W    = (const float*)d_in[3];
    const float* b    = (const float*)d_in[4];
    float* out = (float*)d_out;

    char* ws = (char*)d_ws;
    size_t off = 0;
    ushort* h = (ushort*)(ws + off);        off += (size_t)N_NODES * OUT_F * 2;  // 6.4 MB bf16
    int* outdeg = (int*)(ws + off);         off += (size_t)N_NODES * 4;
    int* indeg = (int*)(ws + off);          off += (size_t)N_NODES * 4;
    int* counter = (int*)(ws + off);        off += 16;
    int* ptr = (int*)(ws + off);            off += (size_t)N_NODES * 4;
    int* bucketBase = (int*)(ws + off);     off += 256 * 4;
    int* gcursor = (int*)(ws + off);        off += 256 * 4;
    uint* pairs = (uint*)(ws + off);        off += (size_t)N_EDGES * 4;          // 3.2 MB
    int* sorted_src = (int*)(ws + off);     off += (size_t)N_EDGES * 4;          // 3.2 MB

    // Zero outdeg+indeg+counter: 2*50000+4 ints = 25001 int4.
    const int n4 = (2 * N_NODES + 4 + 3) / 4;
    zero_kernel<<<(n4 + 255) / 256, 256, 0, stream>>>((int4*)outdeg, n4);

    hist_kernel<<<128, 256, 0, stream>>>(src, dst, outdeg, indeg);

    alloc_kernel<<<NB, 256, 0, stream>>>(indeg, ptr, bucketBase, gcursor, counter);

    partA_kernel<<<PARTA_BLOCKS, 256, 0, stream>>>(src, dst, gcursor, pairs);

    partB_kernel<<<NB, 256, 0, stream>>>(pairs, ptr, bucketBase, gcursor, sorted_src);

    gemm_kernel<<<(N_NODES + 255) / 256, 256, 0, stream>>>(feat, W, outdeg, h);

    gather_kernel<<<(N_NODES * 64 + 255) / 256, 256, 0, stream>>>(ptr, indeg, sorted_src, h, b, out);
}

// Round 9
// 100.653 us; speedup vs baseline: 1.0149x; 1.0149x over previous
//
#include <hip/hip_runtime.h>
#include <hip/hip_bf16.h>
#include <math.h>

#define N_NODES 50000
#define N_EDGES 800000
#define IN_F 256
#define OUT_F 64

#define HIST_CHUNK 12500   // nodes per LDS histogram chunk (4 chunks)
#define HIST_SLICES 32     // edge slices per (array, chunk) -> 256 blocks

#define BKT 256            // nodes per dst-bucket
#define NB 196             // ceil(50000/256)
#define PARTA_BLOCKS 400   // 800000/400 = 2000 edges/block

#define ZERO_BLOCKS 98     // ceil(25001 int4 / 256)

typedef __attribute__((ext_vector_type(8))) short bf16x8;
typedef __attribute__((ext_vector_type(4))) float f32x4;

__device__ __forceinline__ ushort f2bf(float x) {
    __hip_bfloat16 b = __float2bfloat16(x);   // RNE
    return *reinterpret_cast<ushort*>(&b);
}
__device__ __forceinline__ float bf_lo(uint v) { return __uint_as_float(v << 16); }
__device__ __forceinline__ float bf_hi(uint v) { return __uint_as_float(v & 0xffff0000u); }

// ---------------------------------------------------------------------------
// 0) prep: blocks [0,98) zero outdeg+indeg+counter (25001 int4);
//    blocks [98,106) pack W into bf16 MFMA B-frag layout:
//    Wpk[((step*4+ct)*64 + lane)*8 + j] = bf16(W[step*32+(lane>>4)*8+j][ct*16+(lane&15)])
//    (identical values to the old in-loop conversion -> bitwise-same result).
// ---------------------------------------------------------------------------
__global__ __launch_bounds__(256) void prep_kernel(int4* __restrict__ zp, int n4,
                                                   const float* __restrict__ W,
                                                   ushort* __restrict__ Wpk) {
    const int tid = threadIdx.x;
    if (blockIdx.x < ZERO_BLOCKS) {
        const int i = blockIdx.x * 256 + tid;
        if (i < n4) zp[i] = (int4){0, 0, 0, 0};
    } else {
        const int gid = (blockIdx.x - ZERO_BLOCKS) * 256 + tid;   // 0..2047
        const int lane = gid & 63;
        const int ct = (gid >> 6) & 3;
        const int step = gid >> 8;
        const int kg = lane >> 4;
        const int n = lane & 15;
        const float* base = W + (size_t)(step * 32 + kg * 8) * OUT_F + ct * 16 + n;
        union { ushort u[8]; uint4 v; } pk;
        #pragma unroll
        for (int j = 0; j < 8; ++j) pk.u[j] = f2bf(base[(size_t)j * OUT_F]);
        ((uint4*)Wpk)[gid] = pk.v;
    }
}

// ---------------------------------------------------------------------------
// 1) Degree counting via LDS-privatized histograms. 256 blocks (1/CU).
// ---------------------------------------------------------------------------
__global__ __launch_bounds__(256) void hist_kernel(const int* __restrict__ src,
                                                   const int* __restrict__ dst,
                                                   int* __restrict__ outdeg,
                                                   int* __restrict__ indeg) {
    __shared__ int cnt[HIST_CHUNK];   // 50 KB
    const int bi = blockIdx.x;
    const int arr = bi >> 7;
    const int chunk = (bi >> 5) & 3;
    const int slice = bi & 31;
    const int* __restrict__ data = arr ? dst : src;
    int* __restrict__ glob = arr ? indeg : outdeg;
    const int base = chunk * HIST_CHUNK;

    for (int i = threadIdx.x; i < HIST_CHUNK; i += 256) cnt[i] = 0;
    __syncthreads();

    const int4* d4 = (const int4*)(data + (size_t)slice * (N_EDGES / HIST_SLICES));
    for (int i = threadIdx.x; i < (N_EDGES / HIST_SLICES) / 4; i += 256) {
        const int4 v = d4[i];
        int r;
        r = v.x - base; if ((unsigned)r < (unsigned)HIST_CHUNK) atomicAdd(&cnt[r], 1);
        r = v.y - base; if ((unsigned)r < (unsigned)HIST_CHUNK) atomicAdd(&cnt[r], 1);
        r = v.z - base; if ((unsigned)r < (unsigned)HIST_CHUNK) atomicAdd(&cnt[r], 1);
        r = v.w - base; if ((unsigned)r < (unsigned)HIST_CHUNK) atomicAdd(&cnt[r], 1);
    }
    __syncthreads();

    for (int i = threadIdx.x; i < HIST_CHUNK; i += 256) {
        const int c = cnt[i];
        if (c) atomicAdd(&glob[base + i], c);
    }
}

// ---------------------------------------------------------------------------
// 2) Bucket-ordered allocation: one block per 256-node bucket.
// ---------------------------------------------------------------------------
__global__ __launch_bounds__(256) void alloc_kernel(const int* __restrict__ indeg,
                                                    int* __restrict__ ptr,
                                                    int* __restrict__ bucketBase,
                                                    int* __restrict__ gcursor,
                                                    int* __restrict__ counter) {
    __shared__ int wtot[4];
    __shared__ int sbase;
    const int b = blockIdx.x;
    const int tid = threadIdx.x;
    const int lane = tid & 63;
    const int wave = tid >> 6;
    const int node = b * BKT + tid;
    const int v = (node < N_NODES) ? indeg[node] : 0;
    int incl = v;
    #pragma unroll
    for (int d = 1; d < 64; d <<= 1) {
        int u = __shfl_up(incl, d, 64);
        if (lane >= d) incl += u;
    }
    if (lane == 63) wtot[wave] = incl;
    __syncthreads();
    int woff = 0, total = 0;
    #pragma unroll
    for (int w = 0; w < 4; ++w) {
        const int t = wtot[w];
        if (w < wave) woff += t;
        total += t;
    }
    if (tid == 0) sbase = atomicAdd(counter, total);
    __syncthreads();
    const int base = sbase;
    if (node < N_NODES) ptr[node] = base + woff + incl - v;
    if (tid == 0) { bucketBase[b] = base; gcursor[b] = base; }
}

// ---------------------------------------------------------------------------
// 3a) Pass A: partition edges into 196 dst-buckets, packed (dst&255)<<16|src.
// ---------------------------------------------------------------------------
__global__ __launch_bounds__(256) void partA_kernel(const int* __restrict__ src,
                                                    const int* __restrict__ dst,
                                                    int* __restrict__ gcursor,
                                                    uint* __restrict__ pairs) {
    __shared__ int lcnt[NB];
    __shared__ int lbase[NB];
    const int tid = threadIdx.x;
    const int EPB = N_EDGES / PARTA_BLOCKS;   // 2000
    const int n4 = EPB / 4;                   // 500

    for (int i = tid; i < NB; i += 256) lcnt[i] = 0;
    __syncthreads();

    const int4* t4 = (const int4*)(dst + (size_t)blockIdx.x * EPB);
    const int4* s4 = (const int4*)(src + (size_t)blockIdx.x * EPB);

    for (int i = tid; i < n4; i += 256) {
        const int4 d = t4[i];
        atomicAdd(&lcnt[d.x >> 8], 1);
        atomicAdd(&lcnt[d.y >> 8], 1);
        atomicAdd(&lcnt[d.z >> 8], 1);
        atomicAdd(&lcnt[d.w >> 8], 1);
    }
    __syncthreads();

    for (int i = tid; i < NB; i += 256) {
        const int c = lcnt[i];
        lbase[i] = c ? atomicAdd(&gcursor[i], c) : 0;
        lcnt[i] = 0;
    }
    __syncthreads();

    for (int i = tid; i < n4; i += 256) {
        const int4 d = t4[i];
        const int4 s = s4[i];
        int bx, off;
        bx = d.x >> 8; off = atomicAdd(&lcnt[bx], 1);
        pairs[lbase[bx] + off] = ((uint)(d.x & 255) << 16) | (uint)s.x;
        bx = d.y >> 8; off = atomicAdd(&lcnt[bx], 1);
        pairs[lbase[bx] + off] = ((uint)(d.y & 255) << 16) | (uint)s.y;
        bx = d.z >> 8; off = atomicAdd(&lcnt[bx], 1);
        pairs[lbase[bx] + off] = ((uint)(d.z & 255) << 16) | (uint)s.z;
        bx = d.w >> 8; off = atomicAdd(&lcnt[bx], 1);
        pairs[lbase[bx] + off] = ((uint)(d.w & 255) << 16) | (uint)s.w;
    }
}

// ---------------------------------------------------------------------------
// 3b) Pass B: within one bucket, place each src at ptr[dst]+pos (ushort).
// ---------------------------------------------------------------------------
__global__ __launch_bounds__(256) void partB_kernel(const uint* __restrict__ pairs,
                                                    const int* __restrict__ ptr,
                                                    const int* __restrict__ bucketBase,
                                                    const int* __restrict__ gcursor,
                                                    ushort* __restrict__ sorted_src) {
    __shared__ int lptr[BKT];
    __shared__ int lcur[BKT];
    const int b = blockIdx.x;
    const int tid = threadIdx.x;
    const int node = b * BKT + tid;
    lptr[tid] = (node < N_NODES) ? ptr[node] : 0;
    lcur[tid] = 0;
    __syncthreads();
    const int base = bucketBase[b];
    const int cnt = gcursor[b] - base;
    for (int i = tid; i < cnt; i += 256) {
        const uint p = pairs[base + i];
        const int local = (int)(p >> 16);
        const int pos = atomicAdd(&lcur[local], 1);
        sorted_src[lptr[local] + pos] = (ushort)(p & 0xFFFFu);
    }
}

// ---------------------------------------------------------------------------
// 4) h = bf16( norm_src * (feat @ W) ) via MFMA 16x16x32 bf16.
//    Wave = 16 rows x 64 cols; block = 4 waves = 64 rows; grid = 782
//    (3 blocks/CU vs 196-block round-5 version at <1/CU).
//    B-frags are one coalesced 16 B load each from prepacked Wpk.
// ---------------------------------------------------------------------------
__global__ __launch_bounds__(256) void gemm_kernel(const float* __restrict__ feat,
                                                   const ushort* __restrict__ Wpk,
                                                   const int* __restrict__ outdeg,
                                                   ushort* __restrict__ h) {
    const int lane = threadIdx.x & 63;
    const int wave = threadIdx.x >> 6;
    const int m = lane & 15;
    const int g = lane >> 4;
    const int rowBase = blockIdx.x * 64 + wave * 16;

    f32x4 acc[4];
    #pragma unroll
    for (int ct = 0; ct < 4; ++ct) acc[ct] = (f32x4){0.f, 0.f, 0.f, 0.f};

    int arow = rowBase + m;
    if (arow >= N_NODES) arow = N_NODES - 1;   // clamp; stores guarded below
    const float* ap = feat + (size_t)arow * IN_F;
    const bf16x8* wp = (const bf16x8*)Wpk;

    #pragma unroll
    for (int step = 0; step < 8; ++step) {
        const int k0 = step * 32 + g * 8;
        const float4 a0 = *(const float4*)(ap + k0);
        const float4 a1 = *(const float4*)(ap + k0 + 4);
        bf16x8 aa;
        aa[0] = (short)f2bf(a0.x); aa[1] = (short)f2bf(a0.y);
        aa[2] = (short)f2bf(a0.z); aa[3] = (short)f2bf(a0.w);
        aa[4] = (short)f2bf(a1.x); aa[5] = (short)f2bf(a1.y);
        aa[6] = (short)f2bf(a1.z); aa[7] = (short)f2bf(a1.w);
        #pragma unroll
        for (int ct = 0; ct < 4; ++ct)
            acc[ct] = __builtin_amdgcn_mfma_f32_16x16x32_bf16(
                aa, wp[(step * 4 + ct) * 64 + lane], acc[ct], 0, 0, 0);
    }

    // C-frag: col = ct*16 + m, row = rowBase + g*4 + j   [m89 verified]
    #pragma unroll
    for (int j = 0; j < 4; ++j) {
        const int row = rowBase + g * 4 + j;
        if (row < N_NODES) {
            const float norm = rsqrtf(fmaxf((float)outdeg[row], 1.0f));
            #pragma unroll
            for (int ct = 0; ct < 4; ++ct)
                h[(size_t)row * OUT_F + ct * 16 + m] = f2bf(acc[ct][j] * norm);
        }
    }
}

// ---------------------------------------------------------------------------
// 5) Gather + epilogue: one wave per dst node, QUARTER-wave per edge
//    (16 lanes x 8 B = full 128 B h-row), 4 edges per iteration.
// ---------------------------------------------------------------------------
__global__ __launch_bounds__(256) void gather_kernel(const int* __restrict__ ptr,
                                                     const int* __restrict__ indeg,
                                                     const ushort* __restrict__ sorted_src,
                                                     const ushort* __restrict__ h,
                                                     const float* __restrict__ b,
                                                     float* __restrict__ out) {
    const int lane = threadIdx.x & 63;
    const int q = lane & 15;           // col group: cols q*4 .. q*4+3
    const int g = lane >> 4;           // edge slot 0..3
    int nid = (int)((blockIdx.x * (size_t)blockDim.x + threadIdx.x) >> 6);
    if (nid >= N_NODES) return;
    nid = __builtin_amdgcn_readfirstlane(nid);

    const int beg = ptr[nid];
    const int deg = indeg[nid];

    float a0 = 0.f, a1 = 0.f, a2 = 0.f, a3 = 0.f;
    const int nfull = deg >> 2;
    int e = beg + g;
    #pragma unroll 4
    for (int i = 0; i < nfull; ++i) {
        const int s = (int)sorted_src[e];
        e += 4;
        const uint2 v = *(const uint2*)(h + (size_t)s * OUT_F + q * 4);
        a0 += bf_lo(v.x); a1 += bf_hi(v.x);
        a2 += bf_lo(v.y); a3 += bf_hi(v.y);
    }
    const int rem = deg & 3;
    if (g < rem) {
        const int s = (int)sorted_src[beg + (deg & ~3) + g];
        const uint2 v = *(const uint2*)(h + (size_t)s * OUT_F + q * 4);
        a0 += bf_lo(v.x); a1 += bf_hi(v.x);
        a2 += bf_lo(v.y); a3 += bf_hi(v.y);
    }
    // combine the 4 edge-slot groups (flip g bits: xor 16, xor 32)
    a0 += __shfl_xor(a0, 16, 64); a1 += __shfl_xor(a1, 16, 64);
    a2 += __shfl_xor(a2, 16, 64); a3 += __shfl_xor(a3, 16, 64);
    a0 += __shfl_xor(a0, 32, 64); a1 += __shfl_xor(a1, 32, 64);
    a2 += __shfl_xor(a2, 32, 64); a3 += __shfl_xor(a3, 32, 64);

    if (g == 0) {
        const float norm = rsqrtf(fmaxf((float)deg, 1.0f));
        const float4 bb = *(const float4*)(b + q * 4);
        float4 o;
        o.x = 1.0f / (1.0f + expf(-(a0 * norm + bb.x)));
        o.y = 1.0f / (1.0f + expf(-(a1 * norm + bb.y)));
        o.z = 1.0f / (1.0f + expf(-(a2 * norm + bb.z)));
        o.w = 1.0f / (1.0f + expf(-(a3 * norm + bb.w)));
        *(float4*)(out + (size_t)nid * OUT_F + q * 4) = o;
    }
}

// ---------------------------------------------------------------------------
extern "C" void kernel_launch(void* const* d_in, const int* in_sizes, int n_in,
                              void* d_out, int out_size, void* d_ws, size_t ws_size,
                              hipStream_t stream) {
    const float* feat = (const float*)d_in[0];
    const int* src    = (const int*)d_in[1];
    const int* dst    = (const int*)d_in[2];
    const float* W    = (const float*)d_in[3];
    const float* b    = (const float*)d_in[4];
    float* out = (float*)d_out;

    char* ws = (char*)d_ws;
    size_t off = 0;
    ushort* h = (ushort*)(ws + off);        off += (size_t)N_NODES * OUT_F * 2;  // 6.4 MB
    int* outdeg = (int*)(ws + off);         off += (size_t)N_NODES * 4;
    int* indeg = (int*)(ws + off);          off += (size_t)N_NODES * 4;
    int* counter = (int*)(ws + off);        off += 16;
    int* ptr = (int*)(ws + off);            off += (size_t)N_NODES * 4;
    int* bucketBase = (int*)(ws + off);     off += 256 * 4;
    int* gcursor = (int*)(ws + off);        off += 256 * 4;
    uint* pairs = (uint*)(ws + off);        off += (size_t)N_EDGES * 4;          // 3.2 MB
    ushort* sorted_src = (ushort*)(ws + off); off += (size_t)N_EDGES * 2;        // 1.6 MB
    ushort* Wpk = (ushort*)(ws + off);      off += (size_t)IN_F * OUT_F * 2;     // 32 KB

    // prep: zero outdeg+indeg+counter (25001 int4) + pack W (8 blocks).
    const int n4 = (2 * N_NODES + 4 + 3) / 4;
    prep_kernel<<<ZERO_BLOCKS + 8, 256, 0, stream>>>((int4*)outdeg, n4, W, Wpk);

    hist_kernel<<<2 * 4 * HIST_SLICES, 256, 0, stream>>>(src, dst, outdeg, indeg);

    alloc_kernel<<<NB, 256, 0, stream>>>(indeg, ptr, bucketBase, gcursor, counter);

    partA_kernel<<<PARTA_BLOCKS, 256, 0, stream>>>(src, dst, gcursor, pairs);

    partB_kernel<<<NB, 256, 0, stream>>>(pairs, ptr, bucketBase, gcursor, sorted_src);

    gemm_kernel<<<(N_NODES + 63) / 64, 256, 0, stream>>>(feat, Wpk, outdeg, h);

    gather_kernel<<<(N_NODES * 64 + 255) / 256, 256, 0, stream>>>(ptr, indeg, sorted_src, h, b, out);
}